// Round 7
// baseline (402.373 us; speedup 1.0000x reference)
//
#include <hip/hip_runtime.h>
#include <hip/hip_bf16.h>

typedef __bf16 bf16;
typedef __bf16 bf16x4 __attribute__((ext_vector_type(4)));
typedef __bf16 bf16x8 __attribute__((ext_vector_type(8)));
typedef float f32x4 __attribute__((ext_vector_type(4)));

// B=4, T=8, L=512, D=512, H=8, E=64.  BT=32, BTH=256, M=BT*L=16384.

#if __has_builtin(__builtin_amdgcn_exp2f)
#define EXP2(x) __builtin_amdgcn_exp2f(x)
#else
#define EXP2(x) exp2f(x)
#endif

static __device__ __forceinline__ f32x4 mfma16(bf16x4 a, bf16x4 b, f32x4 c) {
#if __has_builtin(__builtin_amdgcn_mfma_f32_16x16x16bf16_1k)
    return __builtin_amdgcn_mfma_f32_16x16x16bf16_1k(a, b, c, 0, 0, 0);
#else
    asm("v_mfma_f32_16x16x16_bf16 %0, %1, %2, %0" : "+v"(c) : "v"(a), "v"(b));
    return c;
#endif
}

// 16B async global->LDS DMA (lds dest = wave-uniform base + lane*16; global
// src per-lane).  Fallback: synchronous copy.
#if __has_builtin(__builtin_amdgcn_global_load_lds)
#define HAVE_GLL 1
#else
#define HAVE_GLL 0
#endif

static __device__ __forceinline__ void gll16(const void* gp, void* lbase, int lane) {
#if HAVE_GLL
    __builtin_amdgcn_global_load_lds(
        (const __attribute__((address_space(1))) void*)gp,
        (__attribute__((address_space(3))) void*)lbase, 16, 0, 0);
#else
    *(uint4*)((char*)lbase + lane * 16) = *(const uint4*)gp;
#endif
}

// ===========================================================================
// prep: W transpose + mask pre-layout + (fused mode) zero the 128 group
// counters used by attn's last-arrival reduction.
// ===========================================================================
static __device__ __forceinline__ void prep_w_job(int job, const float* W0,
                                                  const float* W1, const float* W2,
                                                  bf16* Wt, char* sraw) {
    float(*t)[65] = (float(*)[65])sraw;  // 64*65*4 = 16,640 B
    const int z = job >> 6, sub = job & 63;
    const float* W = (z == 0) ? W0 : (z == 1) ? W1 : W2;
    bf16* O = Wt + (size_t)z * 512 * 512;
    const int d0 = (sub & 7) * 64, n0 = (sub >> 3) * 64;
    {
        int nl = threadIdx.x & 63, dg = threadIdx.x >> 6;
#pragma unroll
        for (int j = 0; j < 16; ++j) {
            int dl = dg + j * 4;
            t[nl][dl] = W[(size_t)(d0 + dl) * 512 + n0 + nl];
        }
    }
    __syncthreads();
    {
        int dl = threadIdx.x & 63, ng = threadIdx.x >> 6;
#pragma unroll
        for (int j = 0; j < 16; ++j) {
            int nl = ng + j * 4;
            O[(size_t)(n0 + nl) * 512 + d0 + dl] = (bf16)t[nl][dl];
        }
    }
}

static __device__ __forceinline__ void prep_mask_job(int bid, const float* maskf,
                                                     bf16* Mp) {
    const int t0 = bid * 256 + threadIdx.x;
    const float4* m4 = (const float4*)maskf;
#pragma unroll
    for (int j = 0; j < 4; ++j) {
        int idx = t0 + j * 16384;
        int q = idx >> 7;
        int sc = idx & 127;
        int cc = sc >> 4;
        int ns = (sc >> 2) & 3;
        int qd = sc & 3;
        float4 v = m4[idx];
        bf16x4 o;
        o[0] = (bf16)v.x; o[1] = (bf16)v.y; o[2] = (bf16)v.z; o[3] = (bf16)v.w;
        size_t off = ((((size_t)(q >> 4) * 8 + cc) * 4 + ns) * 4 + qd) * 64 +
                     (q & 15) * 4;
        *(bf16x4*)&Mp[off] = o;
    }
}

__global__ __launch_bounds__(256) void prep_kernel(const float* W0, const float* W1,
                                                   const float* W2, const float* maskf,
                                                   bf16* Wt, bf16* Mp,
                                                   unsigned* cnt, int zero_cnt) {
    __shared__ __align__(16) char sraw[16640];
    if (zero_cnt && blockIdx.z == 0 && blockIdx.y == 0 && blockIdx.x == 0 &&
        threadIdx.x < 128)
        cnt[threadIdx.x] = 0u;
    if (blockIdx.z == 3) {
        prep_mask_job(blockIdx.y * 8 + blockIdx.x, maskf, Mp);
        return;
    }
    prep_w_job(blockIdx.z * 64 + blockIdx.y * 8 + blockIdx.x, W0, W1, W2, Wt, sraw);
}

// ===========================================================================
// proj (R6-verified v3, unchanged): 128x128 tile, BK=64, 4 waves 2x2,
// B staged via global_load_lds(16) into unpadded [128][64] with XOR slots
// (pre-swizzled global source), A reg-staged in padded [128][72].
// ===========================================================================
static __device__ __forceinline__ void proj_job(int j, const float* __restrict__ Xq,
                                                const float* __restrict__ Xk,
                                                const float* __restrict__ Xv,
                                                const bf16* __restrict__ Wt,
                                                bf16* __restrict__ Qw,
                                                bf16* __restrict__ Kw,
                                                bf16* __restrict__ Vt, char* sraw) {
    bf16* la = (bf16*)sraw;         // [128][72] A
    bf16* lb = (bf16*)sraw + 9216;  // [128][64] B

    const int z = j >> 9, bid = j & 511;
    const float* X = (z == 0) ? Xq : (z == 1) ? Xk : Xv;
    const bf16* W  = Wt + (size_t)z * 512 * 512;
    bf16* Out      = (z == 0) ? Qw : (z == 1) ? Kw : Vt;

    const int tid = threadIdx.x, wave = tid >> 6, lane = tid & 63;
    const int quad = lane >> 4, lc = lane & 15;
    const int wm = wave & 1, wn = wave >> 1;
    const int jj = bid >> 3;
    const int yy = jj & 3;
    const int xt = (bid & 7) * 16 + (jj >> 2);
    const int m0 = xt * 128, n0 = yy * 128;

    f32x4 acc[4][4];
#pragma unroll
    for (int ms = 0; ms < 4; ++ms)
#pragma unroll
        for (int ns = 0; ns < 4; ++ns) acc[ms][ns] = (f32x4){0.f, 0.f, 0.f, 0.f};

    const int ar = tid >> 4, ac = tid & 15;
    const int brl   = lane >> 3;
    const int bslot = lane & 7;
    const int bchunk = bslot ^ brl;

    float4 xr[8];
#pragma unroll
    for (int i = 0; i < 8; ++i)
        xr[i] = *(const float4*)&X[(size_t)(m0 + ar + i * 16) * 512 + ac * 4];

    for (int kb = 0; kb < 512; kb += 64) {
        __syncthreads();
#pragma unroll
        for (int i = 0; i < 4; ++i) {
            int rgrp = wave * 8 + i * 32;
            gll16(&W[(size_t)(n0 + rgrp + brl) * 512 + kb + bchunk * 8],
                  lb + (size_t)rgrp * 64, lane);
        }
#pragma unroll
        for (int i = 0; i < 8; ++i) {
            float4 x = xr[i];
            bf16x4 p;
            p[0] = (bf16)x.x; p[1] = (bf16)x.y; p[2] = (bf16)x.z; p[3] = (bf16)x.w;
            *(bf16x4*)&la[(ar + i * 16) * 72 + ac * 4] = p;
        }
#if HAVE_GLL
        asm volatile("s_waitcnt vmcnt(0)" ::: "memory");
#endif
        __syncthreads();
        if (kb < 448) {
            int kn = kb + 64;
#pragma unroll
            for (int i = 0; i < 8; ++i)
                xr[i] = *(const float4*)&X[(size_t)(m0 + ar + i * 16) * 512 + kn + ac * 4];
        }
#pragma unroll
        for (int kk = 0; kk < 2; ++kk) {
            bf16x8 af[4], bfr[4];
#pragma unroll
            for (int ms = 0; ms < 4; ++ms)
                af[ms] = *(bf16x8*)&la[(wm * 64 + ms * 16 + lc) * 72 + kk * 32 + quad * 8];
#pragma unroll
            for (int ns = 0; ns < 4; ++ns) {
                int row = wn * 64 + ns * 16 + lc;
                int slot = (kk * 4 + quad) ^ (lc & 7);
                bfr[ns] = *(bf16x8*)&lb[(size_t)row * 64 + slot * 8];
            }
#pragma unroll
            for (int ms = 0; ms < 4; ++ms)
#pragma unroll
                for (int ns = 0; ns < 4; ++ns)
                    acc[ms][ns] = __builtin_amdgcn_mfma_f32_16x16x32_bf16(
                        af[ms], bfr[ns], acc[ms][ns], 0, 0, 0);
        }
    }
    // --- epilogue ---
    __syncthreads();
    bf16* lds_c = (bf16*)sraw;
    if (z != 2) {
#pragma unroll
        for (int ms = 0; ms < 4; ++ms)
#pragma unroll
            for (int ns = 0; ns < 4; ++ns)
#pragma unroll
                for (int r = 0; r < 4; ++r)
                    lds_c[(wm * 64 + ms * 16 + quad * 4 + r) * 136 +
                          wn * 64 + ns * 16 + lc] = (bf16)acc[ms][ns][r];
    } else {
#pragma unroll
        for (int ms = 0; ms < 4; ++ms)
#pragma unroll
            for (int ns = 0; ns < 4; ++ns)
#pragma unroll
                for (int r = 0; r < 4; ++r)
                    lds_c[(wn * 64 + ns * 16 + lc) * 136 +
                          wm * 64 + ms * 16 + quad * 4 + r] = (bf16)acc[ms][ns][r];
    }
    __syncthreads();
    const int bt = m0 >> 9, l0 = m0 & 511;
    if (z != 2) {
        const int ec = tid & 7, rg = tid >> 3;
#pragma unroll
        for (int hc = 0; hc < 2; ++hc) {
            int h = (n0 >> 6) + hc;
#pragma unroll
            for (int p = 0; p < 4; ++p) {
                int row = rg + p * 32;
                bf16x8 v = *(bf16x8*)&lds_c[row * 136 + hc * 64 + ec * 8];
                *(bf16x8*)&Out[(((size_t)bt * 8 + h) * 512 + l0 + row) * 64 + ec * 8] = v;
            }
        }
    } else {
        const int rowp = lane >> 2, cc = lane & 3;
#pragma unroll
        for (int pr = 0; pr < 2; ++pr) {
            int row = wave * 32 + pr * 16 + rowp;
            int h = (n0 >> 6) + (row >> 6);
            int e = row & 63;
            bf16* dst = Out + (((size_t)bt * 8 + h) * 64 + e) * 512 + l0;
#pragma unroll
            for (int pc = 0; pc < 4; ++pc) {
                int mc = cc + pc * 4;
                *(bf16x8*)&dst[mc * 8] = *(bf16x8*)&lds_c[row * 136 + mc * 8];
            }
        }
    }
}

__global__ __launch_bounds__(256) void proj_kernel(const float* Xq, const float* Xk,
                                                   const float* Xv, const bf16* Wt,
                                                   bf16* Qw, bf16* Kw, bf16* Vt) {
    __shared__ __align__(16) char sraw[34816];
    int j = blockIdx.z * 512 + blockIdx.y * 128 + blockIdx.x;
    proj_job(j, Xq, Xk, Xv, Wt, Qw, Kw, Vt, sraw);
}

// ===========================================================================
// attn + fused head-reduction.  Loop = R2-verified v9 (mask pre-layout,
// in-register P->PV via 16x16x16, K/V double-buffer, 1 barrier/chunk).
// Epilogue (mode 1): store f32 partials; __threadfence; one atomicAdd on the
// group counter (group = (bt,qquad), 8 h-blocks each); the LAST arrival
// fences and sums the 8 partial streams into out.  No spin -> no deadlock.
// mode 0: atomicAdd fallback (ws too small).
// ===========================================================================
__global__ __launch_bounds__(256, 4) void attn_kernel(
    const bf16* __restrict__ Qw, const bf16* __restrict__ Kw,
    const bf16* __restrict__ Vt, const bf16* __restrict__ Mp,
    const float* __restrict__ w_head, const float* __restrict__ tau,
    const float* __restrict__ delta, float* __restrict__ out,
    float* __restrict__ opart, unsigned* __restrict__ cnt, int mode) {
    __shared__ __align__(16) bf16 lds_k[2][64 * 72];   // [s][e], pad 8
    __shared__ __align__(16) bf16 lds_vt[2][64 * 72];  // [e][s], pad 8
    __shared__ int is_last;

    const int tid  = threadIdx.x;
    const int wave = tid >> 6;
    const int lane = tid & 63;
    const int quad = lane >> 4;
    const int lc   = lane & 15;
    const int b    = blockIdx.x;
    const int bth  = b & 255;
    const int qquad = b >> 8;
    const int bt   = bth >> 3;
    const int h    = bth & 7;

    const bf16* Qh  = Qw + (size_t)bth * (512 * 64);
    const bf16* Kh  = Kw + (size_t)bth * (512 * 64);
    const bf16* VtH = Vt + (size_t)bth * (512 * 64);

    const float L2E = 1.4426950408889634f;
    const float ts = tau[0] * 0.125f * L2E;
    const float ds = delta[0] * 0.125f * L2E;
    const float wh = w_head[h];

    const int q0 = qquad * 128 + wave * 32;
    const size_t mbA = (size_t)(q0 >> 4) * 8192 + lane * 4;
    const size_t mbB = mbA + 8192;

    bf16x8 qfA[2], qfB[2];
#pragma unroll
    for (int kk = 0; kk < 2; ++kk) {
        qfA[kk] = *(const bf16x8*)&Qh[(size_t)(q0 + lc) * 64 + kk * 32 + quad * 8];
        qfB[kk] = *(const bf16x8*)&Qh[(size_t)(q0 + 16 + lc) * 64 + kk * 32 + quad * 8];
    }

    f32x4 oA[4], oB[4];
#pragma unroll
    for (int ns = 0; ns < 4; ++ns) {
        oA[ns] = (f32x4){0.f, 0.f, 0.f, 0.f};
        oB[ns] = (f32x4){0.f, 0.f, 0.f, 0.f};
    }
    float lA = 0.f, lB = 0.f;

    const int srow = tid >> 3, scc = tid & 7;
    bf16x8 kr[2], vr[2];
    kr[0] = *(const bf16x8*)&Kh[(size_t)srow * 64 + scc * 8];
    kr[1] = *(const bf16x8*)&Kh[(size_t)(srow + 32) * 64 + scc * 8];
    vr[0] = *(const bf16x8*)&VtH[(size_t)srow * 512 + scc * 8];
    vr[1] = *(const bf16x8*)&VtH[(size_t)(srow + 32) * 512 + scc * 8];
    *(bf16x8*)&lds_k[0][srow * 72 + scc * 8] = kr[0];
    *(bf16x8*)&lds_k[0][(srow + 32) * 72 + scc * 8] = kr[1];
    *(bf16x8*)&lds_vt[0][srow * 72 + scc * 8] = vr[0];
    *(bf16x8*)&lds_vt[0][(srow + 32) * 72 + scc * 8] = vr[1];
    kr[0] = *(const bf16x8*)&Kh[(size_t)(64 + srow) * 64 + scc * 8];
    kr[1] = *(const bf16x8*)&Kh[(size_t)(64 + srow + 32) * 64 + scc * 8];
    vr[0] = *(const bf16x8*)&VtH[(size_t)srow * 512 + 64 + scc * 8];
    vr[1] = *(const bf16x8*)&VtH[(size_t)(srow + 32) * 512 + 64 + scc * 8];

    for (int c = 0; c < 8; ++c) {
        const int buf = c & 1;
        __syncthreads();
        bf16x4 mA[4], mB[4];
        {
            const size_t mc = mbA + (size_t)c * 1024;
            const size_t md = mbB + (size_t)c * 1024;
#pragma unroll
            for (int ns = 0; ns < 4; ++ns) {
                mA[ns] = *(const bf16x4*)&Mp[mc + ns * 256];
                mB[ns] = *(const bf16x4*)&Mp[md + ns * 256];
            }
        }
        f32x4 stA[4], stB[4];
#pragma unroll
        for (int ns = 0; ns < 4; ++ns) {
            stA[ns] = (f32x4){0.f, 0.f, 0.f, 0.f};
            stB[ns] = (f32x4){0.f, 0.f, 0.f, 0.f};
        }
#pragma unroll
        for (int kk = 0; kk < 2; ++kk)
#pragma unroll
            for (int ns = 0; ns < 4; ++ns) {
                bf16x8 ka = *(bf16x8*)&lds_k[buf][(ns * 16 + lc) * 72 + kk * 32 + quad * 8];
                stA[ns] = __builtin_amdgcn_mfma_f32_16x16x32_bf16(ka, qfA[kk], stA[ns], 0, 0, 0);
                stB[ns] = __builtin_amdgcn_mfma_f32_16x16x32_bf16(ka, qfB[kk], stB[ns], 0, 0, 0);
            }
        if (c < 7) {
            const int nb = buf ^ 1;
            *(bf16x8*)&lds_k[nb][srow * 72 + scc * 8] = kr[0];
            *(bf16x8*)&lds_k[nb][(srow + 32) * 72 + scc * 8] = kr[1];
            *(bf16x8*)&lds_vt[nb][srow * 72 + scc * 8] = vr[0];
            *(bf16x8*)&lds_vt[nb][(srow + 32) * 72 + scc * 8] = vr[1];
            if (c < 6) {
                const int s0n = (c + 2) * 64;
                kr[0] = *(const bf16x8*)&Kh[(size_t)(s0n + srow) * 64 + scc * 8];
                kr[1] = *(const bf16x8*)&Kh[(size_t)(s0n + srow + 32) * 64 + scc * 8];
                vr[0] = *(const bf16x8*)&VtH[(size_t)srow * 512 + s0n + scc * 8];
                vr[1] = *(const bf16x8*)&VtH[(size_t)(srow + 32) * 512 + s0n + scc * 8];
            }
        }
        bf16x4 paA[4], paB[4];
#pragma unroll
        for (int ns = 0; ns < 4; ++ns) {
#pragma unroll
            for (int r = 0; r < 4; ++r) {
                float eA = (stA[ns][r] * ts + ds) * (float)mA[ns][r];
                float eB = (stB[ns][r] * ts + ds) * (float)mB[ns][r];
                float pA = EXP2(eA);
                float pB = EXP2(eB);
                lA += pA; lB += pB;
                paA[ns][r] = (bf16)pA;
                paB[ns][r] = (bf16)pB;
            }
        }
#pragma unroll
        for (int ks = 0; ks < 4; ++ks)
#pragma unroll
            for (int ns = 0; ns < 4; ++ns) {
                bf16x4 vv = *(bf16x4*)&lds_vt[buf][(ns * 16 + lc) * 72 + ks * 16 + quad * 4];
                oA[ns] = mfma16(paA[ks], vv, oA[ns]);
                oB[ns] = mfma16(paB[ks], vv, oB[ns]);
            }
    }
    lA += __shfl_xor(lA, 16, 64);
    lA += __shfl_xor(lA, 32, 64);
    lB += __shfl_xor(lB, 16, 64);
    lB += __shfl_xor(lB, 32, 64);
#pragma unroll
    for (int r = 0; r < 4; ++r) {
        float lrA = __shfl(lA, quad * 4 + r, 64);
        float lrB = __shfl(lB, quad * 4 + r, 64);
        float ivA = wh / lrA, ivB = wh / lrB;
        int qqA = q0 + quad * 4 + r;
        int qqB = q0 + 16 + quad * 4 + r;
        if (mode == 0) {
#pragma unroll
            for (int ns = 0; ns < 4; ++ns) {
                int e = ns * 16 + lc;
                atomicAdd(&out[((size_t)bt * 512 + qqA) * 64 + e], oA[ns][r] * ivA);
                atomicAdd(&out[((size_t)bt * 512 + qqB) * 64 + e], oB[ns][r] * ivB);
            }
        } else {
#pragma unroll
            for (int ns = 0; ns < 4; ++ns) {
                int e = ns * 16 + lc;
                opart[((size_t)bth * 512 + qqA) * 64 + e] = oA[ns][r] * ivA;
                opart[((size_t)bth * 512 + qqB) * 64 + e] = oB[ns][r] * ivB;
            }
        }
    }
    if (mode == 0) return;

    // ---- last-arrival head reduction ----
    __threadfence();   // release this block's partial stores (device scope)
    __syncthreads();
    if (tid == 0) {
        unsigned old = atomicAdd(&cnt[(bt << 2) | qquad], 1u);
        is_last = (old == 7u) ? 1 : 0;
    }
    __syncthreads();
    if (!is_last) return;
    __threadfence();   // acquire: other blocks' partials now visible
    const f32x4* p = (const f32x4*)opart;
    const int qbase = qquad * 128;
#pragma unroll
    for (int k = 0; k < 8; ++k) {
        int t = tid + k * 256;          // 0..2047 float4 of this group's slice
        int q = qbase + (t >> 4);
        int e4 = t & 15;
        f32x4 s = (f32x4){0.f, 0.f, 0.f, 0.f};
#pragma unroll
        for (int hh = 0; hh < 8; ++hh)
            s += p[(size_t)(bt * 8 + hh) * 8192 + (size_t)q * 16 + e4];
        *(f32x4*)&out[(((size_t)bt * 512 + q) * 64) + e4 * 4] = s;
    }
}

// ---------------------------------------------------------------------------
extern "C" void kernel_launch(void* const* d_in, const int* in_sizes, int n_in,
                              void* d_out, int out_size, void* d_ws, size_t ws_size,
                              hipStream_t stream) {
    const float* queries = (const float*)d_in[0];
    const float* keys    = (const float*)d_in[1];
    const float* values  = (const float*)d_in[2];
    const float* mask    = (const float*)d_in[3];
    const float* Wq      = (const float*)d_in[4];
    const float* Wk      = (const float*)d_in[5];
    const float* Wv      = (const float*)d_in[6];
    const float* w_head  = (const float*)d_in[7];
    const float* tau     = (const float*)d_in[8];
    const float* delta   = (const float*)d_in[9];

    char* ws = (char*)d_ws;
    bf16* Qw = (bf16*)(ws);                       // 16,777,216 B
    bf16* Kw = (bf16*)(ws + 16777216ull);         // 16,777,216 B
    bf16* Vt = (bf16*)(ws + 33554432ull);         // 16,777,216 B (V^T [bth][e][s])
    bf16* Wt = (bf16*)(ws + 50331648ull);         //  1,572,864 B
    bf16* Mp = (bf16*)(ws + 51904512ull);         //    524,288 B
    float* Op = (float*)(ws + 52428800ull);       // 33,554,432 B f32 partials
    unsigned* cnt = (unsigned*)(ws + 85983232ull);//       512 B group counters

    // mode 1: partial stores + fused last-arrival reduction (3 dispatches).
    // mode 0: atomicAdd fallback (ws too small).
    int mode = (ws_size >= 85983232ull + 512ull) ? 1 : 0;

    if (mode == 0)
        hipMemsetAsync(d_out, 0, (size_t)out_size * sizeof(float), stream);

    prep_kernel<<<dim3(8, 8, 4), 256, 0, stream>>>(Wq, Wk, Wv, mask, Wt, Mp,
                                                   cnt, mode);

    proj_kernel<<<dim3(128, 4, 3), 256, 0, stream>>>(queries, keys, values, Wt,
                                                     Qw, Kw, Vt);

    attn_kernel<<<1024, 256, 0, stream>>>(Qw, Kw, Vt, Mp, w_head, tau, delta,
                                          (float*)d_out, Op, cnt, mode);
}